// Round 2
// baseline (279.133 us; speedup 1.0000x reference)
//
#include <hip/hip_runtime.h>
#include <hip/hip_bf16.h>
#include <math.h>

#define B 4
#define N 512
#define IN_DIM 128
#define OUT_DIM 128
#define HEADS 4
#define PER_HEAD 32
#define NEG_SLOPE 0.2f

// ---------------------------------------------------------------------------
// Dtype detector: interpret first 4096 uint16 of x as bf16. If the buffer is
// really fp32, the low-half fragments have uniform-random exponent fields ->
// exponents >= 0xE0 (|v|>2^97) appear w.p. ~1/8 per element (certain over 2048
// samples). True bf16 ~N(0,1) never exceeds exponent ~131. flag=1 -> fp32.
// ---------------------------------------------------------------------------
__global__ void detect_dtype(const unsigned short* __restrict__ xb,
                             int* __restrict__ flag) {
    __shared__ int s_f32;
    if (threadIdx.x == 0) s_f32 = 0;
    __syncthreads();
    int local = 0;
    for (int k = threadIdx.x; k < 4096; k += 256) {
        const int e = (xb[k] >> 7) & 0xFF;
        if (e >= 0xE0) local = 1;
    }
    if (local) atomicOr(&s_f32, 1);
    __syncthreads();
    if (threadIdx.x == 0) flag[0] = s_f32;
}

template <bool F32>
__device__ __forceinline__ float ldv(const void* p, int idx) {
    if constexpr (F32) return ((const float*)p)[idx];
    else return __bfloat162float(((const __hip_bfloat16*)p)[idx]);
}

// ---------------------------------------------------------------------------
// Kernel 1: xl = x @ Wl + bl ; xr = x @ Wr + br   (fp32 out to workspace)
// One block per row (B*N rows), 128 threads = one output column each.
// ---------------------------------------------------------------------------
template <bool F32>
__device__ __forceinline__ void gat_linear_body(
    const void* __restrict__ x, const void* __restrict__ Wl,
    const void* __restrict__ bl, const void* __restrict__ Wr,
    const void* __restrict__ br, float* __restrict__ xl,
    float* __restrict__ xr) {
    const int row = blockIdx.x;
    const int col = threadIdx.x;
    __shared__ float xs[IN_DIM];
    xs[col] = ldv<F32>(x, row * IN_DIM + col);
    __syncthreads();
    float accl = ldv<F32>(bl, col);
    float accr = ldv<F32>(br, col);
#pragma unroll 8
    for (int k = 0; k < IN_DIM; ++k) {
        const float xv = xs[k];
        accl += xv * ldv<F32>(Wl, k * OUT_DIM + col);
        accr += xv * ldv<F32>(Wr, k * OUT_DIM + col);
    }
    xl[row * OUT_DIM + col] = accl;
    xr[row * OUT_DIM + col] = accr;
}

__global__ void gat_linear(const void* x, const void* Wl, const void* bl,
                           const void* Wr, const void* br,
                           const int* __restrict__ flag,
                           float* xl, float* xr) {
    if (flag[0]) gat_linear_body<true>(x, Wl, bl, Wr, br, xl, xr);
    else         gat_linear_body<false>(x, Wl, bl, Wr, br, xl, xr);
}

// ---------------------------------------------------------------------------
// Kernel 2: per (b,i): GATv2 scores over all j, segment softmax, aggregate.
// Block = 256 threads = 4 waves; wave h handles head h.
// Lane layout: c = lane&31 (channel), half = lane>>5 (2 j's per iteration).
// ---------------------------------------------------------------------------
template <bool F32>
__device__ __forceinline__ void gat_attn_body(
    const float* __restrict__ xl, const float* __restrict__ xr,
    const int* __restrict__ adj, const void* __restrict__ att,
    const void* __restrict__ bias, void* __restrict__ out) {
    const int i   = blockIdx.x;
    const int b   = blockIdx.y;
    const int tid = threadIdx.x;
    const int h    = tid >> 6;
    const int lane = tid & 63;
    const int c    = lane & 31;
    const int half = lane >> 5;

    __shared__ float e_smem[HEADS][N];

    const float attv = ldv<F32>(att, h * PER_HEAD + c);
    const float xrv  = xr[(b * N + i) * OUT_DIM + h * PER_HEAD + c];

    // scores: e_j = sum_c att[c] * leakyrelu(xr_i[c] + xl_j[c])
    for (int jj = 0; jj < N / 2; ++jj) {
        const int j = 2 * jj + half;
        const float xlv = xl[(b * N + j) * OUT_DIM + h * PER_HEAD + c];
        float s = xrv + xlv;
        s = s > 0.f ? s : NEG_SLOPE * s;
        float p = s * attv;
        p += __shfl_xor(p, 1);
        p += __shfl_xor(p, 2);
        p += __shfl_xor(p, 4);
        p += __shfl_xor(p, 8);
        p += __shfl_xor(p, 16);
        if (c == 0) {
            const bool conn = (adj[(b * N + j) * N + i] != 0) || (j == i);
            e_smem[h][j] = conn ? p : -1e30f;
        }
    }
    __syncthreads();

    // segment softmax over j (wave h owns row h)
    float m = -1e30f;
    for (int j = lane; j < N; j += 64) m = fmaxf(m, e_smem[h][j]);
#pragma unroll
    for (int d = 1; d < 64; d <<= 1) m = fmaxf(m, __shfl_xor(m, d));

    float ssum = 0.f;
    for (int j = lane; j < N; j += 64) {
        const float a = __expf(e_smem[h][j] - m);
        e_smem[h][j] = a;
        ssum += a;
    }
#pragma unroll
    for (int d = 1; d < 64; d <<= 1) ssum += __shfl_xor(ssum, d);
    __syncthreads();

    const float inv = 1.f / ssum;

    // aggregate: out[c] = (sum_j alpha_j * xl[j][c]) * inv + bias
    float acc = 0.f;
    for (int jj = 0; jj < N / 2; ++jj) {
        const int j = 2 * jj + half;
        acc += e_smem[h][j] * xl[(b * N + j) * OUT_DIM + h * PER_HEAD + c];
    }
    acc += __shfl_xor(acc, 32);
    if (half == 0) {
        const float bv = ldv<F32>(bias, h * PER_HEAD + c);
        const float r  = acc * inv + bv;
        const int oidx = (b * N + i) * OUT_DIM + h * PER_HEAD + c;
        if constexpr (F32) ((float*)out)[oidx] = r;
        else ((__hip_bfloat16*)out)[oidx] = __float2bfloat16(r);
    }
}

__global__ void gat_attn(const float* xl, const float* xr, const int* adj,
                         const void* att, const void* bias,
                         const int* __restrict__ flag, void* out) {
    if (flag[0]) gat_attn_body<true>(xl, xr, adj, att, bias, out);
    else         gat_attn_body<false>(xl, xr, adj, att, bias, out);
}

extern "C" void kernel_launch(void* const* d_in, const int* in_sizes, int n_in,
                              void* d_out, int out_size, void* d_ws, size_t ws_size,
                              hipStream_t stream) {
    const void* x    = d_in[0];
    const int*  adj  = (const int*)d_in[1];
    const void* Wl   = d_in[2];
    const void* bl   = d_in[3];
    const void* Wr   = d_in[4];
    const void* br   = d_in[5];
    const void* att  = d_in[6];
    const void* bias = d_in[7];

    float* xl   = (float*)d_ws;                  // 1 MB
    float* xr   = xl + (size_t)B * N * OUT_DIM;  // 1 MB
    int*   flag = (int*)((char*)d_ws + (2u << 20));

    detect_dtype<<<dim3(1), dim3(256), 0, stream>>>((const unsigned short*)x, flag);
    gat_linear<<<dim3(B * N), dim3(128), 0, stream>>>(x, Wl, bl, Wr, br, flag, xl, xr);
    gat_attn<<<dim3(N, B), dim3(256), 0, stream>>>(xl, xr, adj, att, bias, flag, (void*)d_out);
}

// Round 3
// 150.584 us; speedup vs baseline: 1.8537x; 1.8537x over previous
//
#include <hip/hip_runtime.h>
#include <hip/hip_bf16.h>
#include <math.h>

#define B 4
#define N 512
#define IN_DIM 128
#define OUT_DIM 128
#define HEADS 4
#define PER_HEAD 32
#define NT (N / 64)   // 8 j-tiles of 64
#define IT 2          // target nodes per block

// ---------------------------------------------------------------------------
// Dtype detector: fp32-as-bf16 garbage halves show exponent >= 0xE0 w.p. ~1/8
// per element; true bf16 N(0,1) never does. flag=1 -> fp32 inputs.
// (R2 evidence: absmax == 2^-9 exactly => bf16 path is the live one.)
// ---------------------------------------------------------------------------
__global__ void detect_dtype(const unsigned short* __restrict__ xb,
                             int* __restrict__ flag) {
    __shared__ int s_f32;
    if (threadIdx.x == 0) s_f32 = 0;
    __syncthreads();
    int local = 0;
    for (int k = threadIdx.x; k < 4096; k += 256) {
        const int e = (xb[k] >> 7) & 0xFF;
        if (e >= 0xE0) local = 1;
    }
    if (local) atomicOr(&s_f32, 1);
    __syncthreads();
    if (threadIdx.x == 0) flag[0] = s_f32;
}

template <bool F32>
__device__ __forceinline__ float ldv(const void* p, int idx) {
    if constexpr (F32) return ((const float*)p)[idx];
    else return __bfloat162float(((const __hip_bfloat16*)p)[idx]);
}

// ---------------------------------------------------------------------------
// Kernel 1: xl = x@Wl+bl ; xr = x@Wr+br. Also stores xl transposed as
// xlT[b*128 + col][j] for the coalesced per-lane register tile in attn.
// One block per row, 128 threads = one output column each.
// ---------------------------------------------------------------------------
template <bool F32>
__device__ __forceinline__ void gat_linear_body(
    const void* __restrict__ x, const void* __restrict__ Wl,
    const void* __restrict__ bl, const void* __restrict__ Wr,
    const void* __restrict__ br, float* __restrict__ xl,
    float* __restrict__ xr, float* __restrict__ xlT) {
    const int row = blockIdx.x;          // b*N + n
    const int col = threadIdx.x;
    const int b = row >> 9;
    const int n = row & (N - 1);
    __shared__ float xs[IN_DIM];
    xs[col] = ldv<F32>(x, row * IN_DIM + col);
    __syncthreads();
    float accl = ldv<F32>(bl, col);
    float accr = ldv<F32>(br, col);
#pragma unroll 16
    for (int k = 0; k < IN_DIM; ++k) {
        const float xv = xs[k];
        accl += xv * ldv<F32>(Wl, k * OUT_DIM + col);
        accr += xv * ldv<F32>(Wr, k * OUT_DIM + col);
    }
    xl[row * OUT_DIM + col] = accl;
    xr[row * OUT_DIM + col] = accr;
    xlT[(b * OUT_DIM + col) * N + n] = accl;   // scattered 4B store, L2-absorbed
}

__global__ void gat_linear(const void* x, const void* Wl, const void* bl,
                           const void* Wr, const void* br,
                           const int* __restrict__ flag,
                           float* xl, float* xr, float* xlT) {
    if (flag[0]) gat_linear_body<true>(x, Wl, bl, Wr, br, xl, xr, xlT);
    else         gat_linear_body<false>(x, Wl, bl, Wr, br, xl, xr, xlT);
}

// ---------------------------------------------------------------------------
// Kernel 2: adjacency bitmask, transposed + diagonal forced.
// maskT[(b*N+i)*NT + t] bit L = edge (j=t*64+L -> i) exists.
// Wave w handles i = blockIdx.x*4 + w.
// ---------------------------------------------------------------------------
__global__ void gat_mask(const int* __restrict__ adj,
                         unsigned long long* __restrict__ maskT) {
    const int b = blockIdx.y;
    const int i = blockIdx.x * 4 + (threadIdx.x >> 6);
    const int lane = threadIdx.x & 63;
    unsigned long long* mrow = maskT + (size_t)(b * N + i) * NT;
    for (int t = 0; t < NT; ++t) {
        const int j = t * 64 + lane;
        const bool conn = (adj[((size_t)b * N + j) * N + i] != 0) || (j == i);
        const unsigned long long bal = __ballot(conn);
        if (lane == 0) mrow[t] = bal;
    }
}

// ---------------------------------------------------------------------------
// Kernel 3: fused scores + segment-softmax + aggregation.
// Block = 256 thr = 4 waves; wave h = head h; IT target nodes per block.
// Phase 1: lane owns j, xl[j][0..31] in VGPRs, xr/att wave-uniform ->
//          4 VALU per (i,j,c), zero cross-lane ops, bitmask masking.
// Phase 2: register softmax (alpha[NT]/lane), unnormalized alpha -> LDS.
// Phase 3: lane=(jg,c4) float4 aggregation, 12-shuffle reduce, fold 1/sum.
// Waves are fully independent: NO __syncthreads.
// ---------------------------------------------------------------------------
template <bool F32>
__device__ __forceinline__ void gat_attn_body(
    const float* __restrict__ xl, const float* __restrict__ xr,
    const float* __restrict__ xlT,
    const unsigned long long* __restrict__ maskT,
    const void* __restrict__ att, const void* __restrict__ bias,
    void* __restrict__ out) {
    const int tid  = threadIdx.x;
    const int h    = __builtin_amdgcn_readfirstlane(tid >> 6);
    const int lane = tid & 63;
    const int i0   = blockIdx.x * IT;
    const int b    = blockIdx.y;

    __shared__ float a_s[HEADS][IT][N];   // 16 KB, per-wave private rows

    // wave-uniform operands
    float attv[PER_HEAD];
#pragma unroll
    for (int c = 0; c < PER_HEAD; ++c) attv[c] = ldv<F32>(att, h * PER_HEAD + c);
    float xrv[IT][PER_HEAD];
#pragma unroll
    for (int ii = 0; ii < IT; ++ii)
#pragma unroll
        for (int c = 0; c < PER_HEAD; ++c)
            xrv[ii][c] = xr[(b * N + i0 + ii) * OUT_DIM + h * PER_HEAD + c];

    // ---- Phase 1: scores ----
    float e[IT][NT];
    const float* xlTh = xlT + (size_t)(b * OUT_DIM + h * PER_HEAD) * N;
#pragma unroll
    for (int jt = 0; jt < NT; ++jt) {
        const int j = jt * 64 + lane;
        float xlv[PER_HEAD];
#pragma unroll
        for (int c = 0; c < PER_HEAD; ++c) xlv[c] = xlTh[c * N + j];
#pragma unroll
        for (int ii = 0; ii < IT; ++ii) {
            float acc = 0.f;
#pragma unroll
            for (int c = 0; c < PER_HEAD; ++c) {
                const float s = xrv[ii][c] + xlv[c];
                const float lr = fmaxf(s, 0.2f * s);
                acc = fmaf(attv[c], lr, acc);
            }
            const unsigned long long m = maskT[(size_t)(b * N + i0 + ii) * NT + jt];
            e[ii][jt] = ((m >> lane) & 1ull) ? acc : -1e30f;
        }
    }

    // ---- Phase 2: softmax (register), alpha -> LDS ----
    float inv[IT];
#pragma unroll
    for (int ii = 0; ii < IT; ++ii) {
        float m = e[ii][0];
#pragma unroll
        for (int t = 1; t < NT; ++t) m = fmaxf(m, e[ii][t]);
#pragma unroll
        for (int d = 1; d < 64; d <<= 1) m = fmaxf(m, __shfl_xor(m, d));
        float ssum = 0.f;
#pragma unroll
        for (int t = 0; t < NT; ++t) {
            const float a = __expf(e[ii][t] - m);
            a_s[h][ii][t * 64 + lane] = a;
            ssum += a;
        }
#pragma unroll
        for (int d = 1; d < 64; d <<= 1) ssum += __shfl_xor(ssum, d);
        inv[ii] = 1.f / ssum;
    }
    // same wave wrote a_s[h][*] -> no barrier needed (lgkmcnt ordering only)

    // ---- Phase 3: aggregation ----
    const int c4 = (lane & 7) * 4;   // 4 channels per lane
    const int jg = lane >> 3;        // 8 j's per iteration
    float bv[4];
#pragma unroll
    for (int k = 0; k < 4; ++k) bv[k] = ldv<F32>(bias, h * PER_HEAD + c4 + k);

#pragma unroll
    for (int ii = 0; ii < IT; ++ii) {
        float ax = 0.f, ay = 0.f, az = 0.f, aw = 0.f;
        for (int jo = 0; jo < N / 8; ++jo) {
            const int j = jo * 8 + jg;
            const float av = a_s[h][ii][j];
            const float4 xv =
                *(const float4*)&xl[(b * N + j) * OUT_DIM + h * PER_HEAD + c4];
            ax = fmaf(av, xv.x, ax);
            ay = fmaf(av, xv.y, ay);
            az = fmaf(av, xv.z, az);
            aw = fmaf(av, xv.w, aw);
        }
#pragma unroll
        for (int d = 8; d < 64; d <<= 1) {
            ax += __shfl_xor(ax, d);
            ay += __shfl_xor(ay, d);
            az += __shfl_xor(az, d);
            aw += __shfl_xor(aw, d);
        }
        if (jg == 0) {
            const float s = inv[ii];
            const float r0 = ax * s + bv[0];
            const float r1 = ay * s + bv[1];
            const float r2 = az * s + bv[2];
            const float r3 = aw * s + bv[3];
            const int ob = (b * N + i0 + ii) * OUT_DIM + h * PER_HEAD + c4;
            if constexpr (F32) {
                *(float4*)((float*)out + ob) = make_float4(r0, r1, r2, r3);
            } else {
                union { ushort4 u; __hip_bfloat16 h4[4]; } cv;
                cv.h4[0] = __float2bfloat16(r0);
                cv.h4[1] = __float2bfloat16(r1);
                cv.h4[2] = __float2bfloat16(r2);
                cv.h4[3] = __float2bfloat16(r3);
                *(ushort4*)((__hip_bfloat16*)out + ob) = cv.u;
            }
        }
    }
}

__global__ void gat_attn(const float* xl, const float* xr, const float* xlT,
                         const unsigned long long* maskT, const void* att,
                         const void* bias, const int* __restrict__ flag,
                         void* out) {
    if (flag[0]) gat_attn_body<true>(xl, xr, xlT, maskT, att, bias, out);
    else         gat_attn_body<false>(xl, xr, xlT, maskT, att, bias, out);
}

extern "C" void kernel_launch(void* const* d_in, const int* in_sizes, int n_in,
                              void* d_out, int out_size, void* d_ws, size_t ws_size,
                              hipStream_t stream) {
    const void* x    = d_in[0];
    const int*  adj  = (const int*)d_in[1];
    const void* Wl   = d_in[2];
    const void* bl   = d_in[3];
    const void* Wr   = d_in[4];
    const void* br   = d_in[5];
    const void* att  = d_in[6];
    const void* bias = d_in[7];

    char* ws = (char*)d_ws;
    float* xl   = (float*)(ws);                         // 1 MB
    float* xr   = (float*)(ws + (1u << 20));            // 1 MB
    float* xlT  = (float*)(ws + (2u << 20));            // 1 MB
    unsigned long long* maskT =
        (unsigned long long*)(ws + (3u << 20));         // 128 KB
    int* flag = (int*)(ws + (3u << 20) + (1u << 17));

    detect_dtype<<<dim3(1), dim3(256), 0, stream>>>((const unsigned short*)x, flag);
    gat_linear<<<dim3(B * N), dim3(128), 0, stream>>>(x, Wl, bl, Wr, br, flag,
                                                      xl, xr, xlT);
    gat_mask<<<dim3(N / 4, B), dim3(256), 0, stream>>>(adj, maskT);
    gat_attn<<<dim3(N / IT, B), dim3(256), 0, stream>>>(xl, xr, xlT, maskT, att,
                                                        bias, flag, (void*)d_out);
}

// Round 6
// 139.806 us; speedup vs baseline: 1.9966x; 1.0771x over previous
//
#include <hip/hip_runtime.h>
#include <hip/hip_bf16.h>
#include <math.h>

#define B 4
#define N 512
#define IN_DIM 128
#define OUT_DIM 128
#define HEADS 4
#define PER_HEAD 32
#define NT (N / 64)   // 8 j-tiles of 64
#define IT 2          // target nodes per block

// R6 = byte-exact R3 source (last green) + ONE change: __launch_bounds__(256)
// on gat_attn, to lift the default-1024-flat-workgroup 64-VGPR cap that
// caused 35 MB/dispatch scratch spill traffic in R3. Single-variable bisect:
// R4/R5 changed linear+mask+attn simultaneously and NaN'd.

__global__ void detect_dtype(const unsigned short* __restrict__ xb,
                             int* __restrict__ flag) {
    __shared__ int s_f32;
    if (threadIdx.x == 0) s_f32 = 0;
    __syncthreads();
    int local = 0;
    for (int k = threadIdx.x; k < 4096; k += 256) {
        const int e = (xb[k] >> 7) & 0xFF;
        if (e >= 0xE0) local = 1;
    }
    if (local) atomicOr(&s_f32, 1);
    __syncthreads();
    if (threadIdx.x == 0) flag[0] = s_f32;
}

template <bool F32>
__device__ __forceinline__ float ldv(const void* p, int idx) {
    if constexpr (F32) return ((const float*)p)[idx];
    else return __bfloat162float(((const __hip_bfloat16*)p)[idx]);
}

template <bool F32>
__device__ __forceinline__ void gat_linear_body(
    const void* __restrict__ x, const void* __restrict__ Wl,
    const void* __restrict__ bl, const void* __restrict__ Wr,
    const void* __restrict__ br, float* __restrict__ xl,
    float* __restrict__ xr, float* __restrict__ xlT) {
    const int row = blockIdx.x;          // b*N + n
    const int col = threadIdx.x;
    const int b = row >> 9;
    const int n = row & (N - 1);
    __shared__ float xs[IN_DIM];
    xs[col] = ldv<F32>(x, row * IN_DIM + col);
    __syncthreads();
    float accl = ldv<F32>(bl, col);
    float accr = ldv<F32>(br, col);
#pragma unroll 16
    for (int k = 0; k < IN_DIM; ++k) {
        const float xv = xs[k];
        accl += xv * ldv<F32>(Wl, k * OUT_DIM + col);
        accr += xv * ldv<F32>(Wr, k * OUT_DIM + col);
    }
    xl[row * OUT_DIM + col] = accl;
    xr[row * OUT_DIM + col] = accr;
    xlT[(b * OUT_DIM + col) * N + n] = accl;   // scattered 4B store, L2-absorbed
}

__global__ void gat_linear(const void* x, const void* Wl, const void* bl,
                           const void* Wr, const void* br,
                           const int* __restrict__ flag,
                           float* xl, float* xr, float* xlT) {
    if (flag[0]) gat_linear_body<true>(x, Wl, bl, Wr, br, xl, xr, xlT);
    else         gat_linear_body<false>(x, Wl, bl, Wr, br, xl, xr, xlT);
}

__global__ void gat_mask(const int* __restrict__ adj,
                         unsigned long long* __restrict__ maskT) {
    const int b = blockIdx.y;
    const int i = blockIdx.x * 4 + (threadIdx.x >> 6);
    const int lane = threadIdx.x & 63;
    unsigned long long* mrow = maskT + (size_t)(b * N + i) * NT;
    for (int t = 0; t < NT; ++t) {
        const int j = t * 64 + lane;
        const bool conn = (adj[((size_t)b * N + j) * N + i] != 0) || (j == i);
        const unsigned long long bal = __ballot(conn);
        if (lane == 0) mrow[t] = bal;
    }
}

template <bool F32>
__device__ __forceinline__ void gat_attn_body(
    const float* __restrict__ xl, const float* __restrict__ xr,
    const float* __restrict__ xlT,
    const unsigned long long* __restrict__ maskT,
    const void* __restrict__ att, const void* __restrict__ bias,
    void* __restrict__ out) {
    const int tid  = threadIdx.x;
    const int h    = __builtin_amdgcn_readfirstlane(tid >> 6);
    const int lane = tid & 63;
    const int i0   = blockIdx.x * IT;
    const int b    = blockIdx.y;

    __shared__ float a_s[HEADS][IT][N];   // 16 KB, per-wave private rows

    float attv[PER_HEAD];
#pragma unroll
    for (int c = 0; c < PER_HEAD; ++c) attv[c] = ldv<F32>(att, h * PER_HEAD + c);
    float xrv[IT][PER_HEAD];
#pragma unroll
    for (int ii = 0; ii < IT; ++ii)
#pragma unroll
        for (int c = 0; c < PER_HEAD; ++c)
            xrv[ii][c] = xr[(b * N + i0 + ii) * OUT_DIM + h * PER_HEAD + c];

    // ---- Phase 1: scores ----
    float e[IT][NT];
    const float* xlTh = xlT + (size_t)(b * OUT_DIM + h * PER_HEAD) * N;
#pragma unroll
    for (int jt = 0; jt < NT; ++jt) {
        const int j = jt * 64 + lane;
        float xlv[PER_HEAD];
#pragma unroll
        for (int c = 0; c < PER_HEAD; ++c) xlv[c] = xlTh[c * N + j];
#pragma unroll
        for (int ii = 0; ii < IT; ++ii) {
            float acc = 0.f;
#pragma unroll
            for (int c = 0; c < PER_HEAD; ++c) {
                const float s = xrv[ii][c] + xlv[c];
                const float lr = fmaxf(s, 0.2f * s);
                acc = fmaf(attv[c], lr, acc);
            }
            const unsigned long long m = maskT[(size_t)(b * N + i0 + ii) * NT + jt];
            e[ii][jt] = ((m >> lane) & 1ull) ? acc : -1e30f;
        }
    }

    // ---- Phase 2: softmax (register), unnormalized alpha -> LDS ----
    float inv[IT];
#pragma unroll
    for (int ii = 0; ii < IT; ++ii) {
        float m = e[ii][0];
#pragma unroll
        for (int t = 1; t < NT; ++t) m = fmaxf(m, e[ii][t]);
#pragma unroll
        for (int d = 1; d < 64; d <<= 1) m = fmaxf(m, __shfl_xor(m, d));
        float ssum = 0.f;
#pragma unroll
        for (int t = 0; t < NT; ++t) {
            const float a = __expf(e[ii][t] - m);
            a_s[h][ii][t * 64 + lane] = a;
            ssum += a;
        }
#pragma unroll
        for (int d = 1; d < 64; d <<= 1) ssum += __shfl_xor(ssum, d);
        inv[ii] = 1.f / ssum;
    }
    // same wave wrote a_s[h][*] -> no barrier needed

    // ---- Phase 3: aggregation ----
    const int c4 = (lane & 7) * 4;
    const int jg = lane >> 3;
    float bv[4];
#pragma unroll
    for (int k = 0; k < 4; ++k) bv[k] = ldv<F32>(bias, h * PER_HEAD + c4 + k);

#pragma unroll
    for (int ii = 0; ii < IT; ++ii) {
        float ax = 0.f, ay = 0.f, az = 0.f, aw = 0.f;
        for (int jo = 0; jo < N / 8; ++jo) {
            const int j = jo * 8 + jg;
            const float av = a_s[h][ii][j];
            const float4 xv =
                *(const float4*)&xl[(b * N + j) * OUT_DIM + h * PER_HEAD + c4];
            ax = fmaf(av, xv.x, ax);
            ay = fmaf(av, xv.y, ay);
            az = fmaf(av, xv.z, az);
            aw = fmaf(av, xv.w, aw);
        }
#pragma unroll
        for (int d = 8; d < 64; d <<= 1) {
            ax += __shfl_xor(ax, d);
            ay += __shfl_xor(ay, d);
            az += __shfl_xor(az, d);
            aw += __shfl_xor(aw, d);
        }
        if (jg == 0) {
            const float s = inv[ii];
            const float r0 = ax * s + bv[0];
            const float r1 = ay * s + bv[1];
            const float r2 = az * s + bv[2];
            const float r3 = aw * s + bv[3];
            const int ob = (b * N + i0 + ii) * OUT_DIM + h * PER_HEAD + c4;
            if constexpr (F32) {
                *(float4*)((float*)out + ob) = make_float4(r0, r1, r2, r3);
            } else {
                union { ushort4 u; __hip_bfloat16 h4[4]; } cv;
                cv.h4[0] = __float2bfloat16(r0);
                cv.h4[1] = __float2bfloat16(r1);
                cv.h4[2] = __float2bfloat16(r2);
                cv.h4[3] = __float2bfloat16(r3);
                *(ushort4*)((__hip_bfloat16*)out + ob) = cv.u;
            }
        }
    }
}

__global__ __launch_bounds__(256) void gat_attn(
    const float* xl, const float* xr, const float* xlT,
    const unsigned long long* maskT, const void* att,
    const void* bias, const int* __restrict__ flag,
    void* out) {
    if (flag[0]) gat_attn_body<true>(xl, xr, xlT, maskT, att, bias, out);
    else         gat_attn_body<false>(xl, xr, xlT, maskT, att, bias, out);
}

extern "C" void kernel_launch(void* const* d_in, const int* in_sizes, int n_in,
                              void* d_out, int out_size, void* d_ws, size_t ws_size,
                              hipStream_t stream) {
    const void* x    = d_in[0];
    const int*  adj  = (const int*)d_in[1];
    const void* Wl   = d_in[2];
    const void* bl   = d_in[3];
    const void* Wr   = d_in[4];
    const void* br   = d_in[5];
    const void* att  = d_in[6];
    const void* bias = d_in[7];

    char* ws = (char*)d_ws;
    float* xl   = (float*)(ws);                         // 1 MB
    float* xr   = (float*)(ws + (1u << 20));            // 1 MB
    float* xlT  = (float*)(ws + (2u << 20));            // 1 MB
    unsigned long long* maskT =
        (unsigned long long*)(ws + (3u << 20));         // 128 KB
    int* flag = (int*)(ws + (3u << 20) + (1u << 17));

    detect_dtype<<<dim3(1), dim3(256), 0, stream>>>((const unsigned short*)x, flag);
    gat_linear<<<dim3(B * N), dim3(128), 0, stream>>>(x, Wl, bl, Wr, br, flag,
                                                      xl, xr, xlT);
    gat_mask<<<dim3(N / 4, B), dim3(256), 0, stream>>>(adj, maskT);
    gat_attn<<<dim3(N / IT, B), dim3(256), 0, stream>>>(xl, xr, xlT, maskT, att,
                                                        bias, flag, (void*)d_out);
}

// Round 7
// 137.534 us; speedup vs baseline: 2.0296x; 1.0165x over previous
//
#include <hip/hip_runtime.h>
#include <hip/hip_bf16.h>
#include <math.h>

#define B 4
#define N 512
#define IN_DIM 128
#define OUT_DIM 128
#define HEADS 4
#define PER_HEAD 32
#define NT (N / 64)   // 8 j-tiles of 64
#define IT 2          // target nodes per block

// R7 = green R6 + ONE change: gat_attn block = 1 wave (64 thr, one head),
// grid (N/IT, H, B). R6 evidence: OccupancyPercent ~9.9% == 1 four-wave
// block/CU (54us == 1024 blocks x 13.5us / 256 CU serial); 1-wave blocks
// let the scheduler pack to the VGPR limit (12 waves/CU) regardless of
// block-granularity constraints. linear/mask/detect byte-identical to R6.

__global__ void detect_dtype(const unsigned short* __restrict__ xb,
                             int* __restrict__ flag) {
    __shared__ int s_f32;
    if (threadIdx.x == 0) s_f32 = 0;
    __syncthreads();
    int local = 0;
    for (int k = threadIdx.x; k < 4096; k += 256) {
        const int e = (xb[k] >> 7) & 0xFF;
        if (e >= 0xE0) local = 1;
    }
    if (local) atomicOr(&s_f32, 1);
    __syncthreads();
    if (threadIdx.x == 0) flag[0] = s_f32;
}

template <bool F32>
__device__ __forceinline__ float ldv(const void* p, int idx) {
    if constexpr (F32) return ((const float*)p)[idx];
    else return __bfloat162float(((const __hip_bfloat16*)p)[idx]);
}

template <bool F32>
__device__ __forceinline__ void gat_linear_body(
    const void* __restrict__ x, const void* __restrict__ Wl,
    const void* __restrict__ bl, const void* __restrict__ Wr,
    const void* __restrict__ br, float* __restrict__ xl,
    float* __restrict__ xr, float* __restrict__ xlT) {
    const int row = blockIdx.x;          // b*N + n
    const int col = threadIdx.x;
    const int b = row >> 9;
    const int n = row & (N - 1);
    __shared__ float xs[IN_DIM];
    xs[col] = ldv<F32>(x, row * IN_DIM + col);
    __syncthreads();
    float accl = ldv<F32>(bl, col);
    float accr = ldv<F32>(br, col);
#pragma unroll 16
    for (int k = 0; k < IN_DIM; ++k) {
        const float xv = xs[k];
        accl += xv * ldv<F32>(Wl, k * OUT_DIM + col);
        accr += xv * ldv<F32>(Wr, k * OUT_DIM + col);
    }
    xl[row * OUT_DIM + col] = accl;
    xr[row * OUT_DIM + col] = accr;
    xlT[(b * OUT_DIM + col) * N + n] = accl;   // scattered 4B store, L2-absorbed
}

__global__ void gat_linear(const void* x, const void* Wl, const void* bl,
                           const void* Wr, const void* br,
                           const int* __restrict__ flag,
                           float* xl, float* xr, float* xlT) {
    if (flag[0]) gat_linear_body<true>(x, Wl, bl, Wr, br, xl, xr, xlT);
    else         gat_linear_body<false>(x, Wl, bl, Wr, br, xl, xr, xlT);
}

__global__ void gat_mask(const int* __restrict__ adj,
                         unsigned long long* __restrict__ maskT) {
    const int b = blockIdx.y;
    const int i = blockIdx.x * 4 + (threadIdx.x >> 6);
    const int lane = threadIdx.x & 63;
    unsigned long long* mrow = maskT + (size_t)(b * N + i) * NT;
    for (int t = 0; t < NT; ++t) {
        const int j = t * 64 + lane;
        const bool conn = (adj[((size_t)b * N + j) * N + i] != 0) || (j == i);
        const unsigned long long bal = __ballot(conn);
        if (lane == 0) mrow[t] = bal;
    }
}

template <bool F32>
__device__ __forceinline__ void gat_attn_body(
    const float* __restrict__ xl, const float* __restrict__ xr,
    const float* __restrict__ xlT,
    const unsigned long long* __restrict__ maskT,
    const void* __restrict__ att, const void* __restrict__ bias,
    void* __restrict__ out) {
    const int lane = threadIdx.x;         // 0..63 (one wave)
    const int h    = blockIdx.y;          // head
    const int i0   = blockIdx.x * IT;
    const int b    = blockIdx.z;

    __shared__ float a_s[IT][N];          // 4 KB, single-wave private

    float attv[PER_HEAD];
#pragma unroll
    for (int c = 0; c < PER_HEAD; ++c) attv[c] = ldv<F32>(att, h * PER_HEAD + c);
    float xrv[IT][PER_HEAD];
#pragma unroll
    for (int ii = 0; ii < IT; ++ii)
#pragma unroll
        for (int c = 0; c < PER_HEAD; ++c)
            xrv[ii][c] = xr[(b * N + i0 + ii) * OUT_DIM + h * PER_HEAD + c];

    // ---- Phase 1: scores ----
    float e[IT][NT];
    const float* xlTh = xlT + (size_t)(b * OUT_DIM + h * PER_HEAD) * N;
#pragma unroll
    for (int jt = 0; jt < NT; ++jt) {
        const int j = jt * 64 + lane;
        float xlv[PER_HEAD];
#pragma unroll
        for (int c = 0; c < PER_HEAD; ++c) xlv[c] = xlTh[c * N + j];
#pragma unroll
        for (int ii = 0; ii < IT; ++ii) {
            float acc = 0.f;
#pragma unroll
            for (int c = 0; c < PER_HEAD; ++c) {
                const float s = xrv[ii][c] + xlv[c];
                const float lr = fmaxf(s, 0.2f * s);
                acc = fmaf(attv[c], lr, acc);
            }
            const unsigned long long m = maskT[(size_t)(b * N + i0 + ii) * NT + jt];
            e[ii][jt] = ((m >> lane) & 1ull) ? acc : -1e30f;
        }
    }

    // ---- Phase 2: softmax (register), unnormalized alpha -> LDS ----
    float inv[IT];
#pragma unroll
    for (int ii = 0; ii < IT; ++ii) {
        float m = e[ii][0];
#pragma unroll
        for (int t = 1; t < NT; ++t) m = fmaxf(m, e[ii][t]);
#pragma unroll
        for (int d = 1; d < 64; d <<= 1) m = fmaxf(m, __shfl_xor(m, d));
        float ssum = 0.f;
#pragma unroll
        for (int t = 0; t < NT; ++t) {
            const float a = __expf(e[ii][t] - m);
            a_s[ii][t * 64 + lane] = a;
            ssum += a;
        }
#pragma unroll
        for (int d = 1; d < 64; d <<= 1) ssum += __shfl_xor(ssum, d);
        inv[ii] = 1.f / ssum;
    }
    // same wave wrote a_s -> no barrier needed

    // ---- Phase 3: aggregation ----
    const int c4 = (lane & 7) * 4;
    const int jg = lane >> 3;
    float bv[4];
#pragma unroll
    for (int k = 0; k < 4; ++k) bv[k] = ldv<F32>(bias, h * PER_HEAD + c4 + k);

#pragma unroll
    for (int ii = 0; ii < IT; ++ii) {
        float ax = 0.f, ay = 0.f, az = 0.f, aw = 0.f;
        for (int jo = 0; jo < N / 8; ++jo) {
            const int j = jo * 8 + jg;
            const float av = a_s[ii][j];
            const float4 xv =
                *(const float4*)&xl[(b * N + j) * OUT_DIM + h * PER_HEAD + c4];
            ax = fmaf(av, xv.x, ax);
            ay = fmaf(av, xv.y, ay);
            az = fmaf(av, xv.z, az);
            aw = fmaf(av, xv.w, aw);
        }
#pragma unroll
        for (int d = 8; d < 64; d <<= 1) {
            ax += __shfl_xor(ax, d);
            ay += __shfl_xor(ay, d);
            az += __shfl_xor(az, d);
            aw += __shfl_xor(aw, d);
        }
        if (jg == 0) {
            const float s = inv[ii];
            const float r0 = ax * s + bv[0];
            const float r1 = ay * s + bv[1];
            const float r2 = az * s + bv[2];
            const float r3 = aw * s + bv[3];
            const int ob = (b * N + i0 + ii) * OUT_DIM + h * PER_HEAD + c4;
            if constexpr (F32) {
                *(float4*)((float*)out + ob) = make_float4(r0, r1, r2, r3);
            } else {
                union { ushort4 u; __hip_bfloat16 h4[4]; } cv;
                cv.h4[0] = __float2bfloat16(r0);
                cv.h4[1] = __float2bfloat16(r1);
                cv.h4[2] = __float2bfloat16(r2);
                cv.h4[3] = __float2bfloat16(r3);
                *(ushort4*)((__hip_bfloat16*)out + ob) = cv.u;
            }
        }
    }
}

__global__ __launch_bounds__(64) void gat_attn(
    const float* xl, const float* xr, const float* xlT,
    const unsigned long long* maskT, const void* att,
    const void* bias, const int* __restrict__ flag,
    void* out) {
    if (flag[0]) gat_attn_body<true>(xl, xr, xlT, maskT, att, bias, out);
    else         gat_attn_body<false>(xl, xr, xlT, maskT, att, bias, out);
}

extern "C" void kernel_launch(void* const* d_in, const int* in_sizes, int n_in,
                              void* d_out, int out_size, void* d_ws, size_t ws_size,
                              hipStream_t stream) {
    const void* x    = d_in[0];
    const int*  adj  = (const int*)d_in[1];
    const void* Wl   = d_in[2];
    const void* bl   = d_in[3];
    const void* Wr   = d_in[4];
    const void* br   = d_in[5];
    const void* att  = d_in[6];
    const void* bias = d_in[7];

    char* ws = (char*)d_ws;
    float* xl   = (float*)(ws);                         // 1 MB
    float* xr   = (float*)(ws + (1u << 20));            // 1 MB
    float* xlT  = (float*)(ws + (2u << 20));            // 1 MB
    unsigned long long* maskT =
        (unsigned long long*)(ws + (3u << 20));         // 128 KB
    int* flag = (int*)(ws + (3u << 20) + (1u << 17));

    detect_dtype<<<dim3(1), dim3(256), 0, stream>>>((const unsigned short*)x, flag);
    gat_linear<<<dim3(B * N), dim3(128), 0, stream>>>(x, Wl, bl, Wr, br, flag,
                                                      xl, xr, xlT);
    gat_mask<<<dim3(N / 4, B), dim3(256), 0, stream>>>(adj, maskT);
    gat_attn<<<dim3(N / IT, HEADS, B), dim3(64), 0, stream>>>(xl, xr, xlT, maskT,
                                                              att, bias, flag,
                                                              (void*)d_out);
}

// Round 8
// 128.492 us; speedup vs baseline: 2.1724x; 1.0704x over previous
//
#include <hip/hip_runtime.h>
#include <hip/hip_bf16.h>
#include <math.h>

#define B 4
#define N 512
#define IN_DIM 128
#define OUT_DIM 128
#define HEADS 4
#define PER_HEAD 32
#define NT (N / 64)   // 8 j-tiles of 64
#define IT 2          // target nodes per block

// R8 = green R7 + attn-local ILP fixes:
//  (1) phase-3 jo-loop unrolled x8 (R7: 1 dependent L2 float4/iter -> ~20k cyc
//      serialized stall per wave; 4096 waves x ~24k cyc explains 53us).
//  (2) xlT stored in channel-group-of-4 layout so phase 1 loads 8x float4
//      per tile instead of 32 scalar 4B loads (same bytes, 4x fewer issues).
// detect/linear(core)/mask byte-stable from R7 (R4/R5 NaN still unattributed).

__global__ void detect_dtype(const unsigned short* __restrict__ xb,
                             int* __restrict__ flag) {
    __shared__ int s_f32;
    if (threadIdx.x == 0) s_f32 = 0;
    __syncthreads();
    int local = 0;
    for (int k = threadIdx.x; k < 4096; k += 256) {
        const int e = (xb[k] >> 7) & 0xFF;
        if (e >= 0xE0) local = 1;
    }
    if (local) atomicOr(&s_f32, 1);
    __syncthreads();
    if (threadIdx.x == 0) flag[0] = s_f32;
}

template <bool F32>
__device__ __forceinline__ float ldv(const void* p, int idx) {
    if constexpr (F32) return ((const float*)p)[idx];
    else return __bfloat162float(((const __hip_bfloat16*)p)[idx]);
}

// xlT layout: xlT[((b*32 + cg)*N + n)*4 + cl], cg = channel>>2, cl = channel&3
// -> for a fixed head, 8 float4-rows of length N, float4 index (b*32+cg)*N + j.
template <bool F32>
__device__ __forceinline__ void gat_linear_body(
    const void* __restrict__ x, const void* __restrict__ Wl,
    const void* __restrict__ bl, const void* __restrict__ Wr,
    const void* __restrict__ br, float* __restrict__ xl,
    float* __restrict__ xr, float* __restrict__ xlT) {
    const int row = blockIdx.x;          // b*N + n
    const int col = threadIdx.x;
    const int b = row >> 9;
    const int n = row & (N - 1);
    __shared__ float xs[IN_DIM];
    xs[col] = ldv<F32>(x, row * IN_DIM + col);
    __syncthreads();
    float accl = ldv<F32>(bl, col);
    float accr = ldv<F32>(br, col);
#pragma unroll 16
    for (int k = 0; k < IN_DIM; ++k) {
        const float xv = xs[k];
        accl += xv * ldv<F32>(Wl, k * OUT_DIM + col);
        accr += xv * ldv<F32>(Wr, k * OUT_DIM + col);
    }
    xl[row * OUT_DIM + col] = accl;
    xr[row * OUT_DIM + col] = accr;
    xlT[((b * 32 + (col >> 2)) * N + n) * 4 + (col & 3)] = accl;
}

__global__ void gat_linear(const void* x, const void* Wl, const void* bl,
                           const void* Wr, const void* br,
                           const int* __restrict__ flag,
                           float* xl, float* xr, float* xlT) {
    if (flag[0]) gat_linear_body<true>(x, Wl, bl, Wr, br, xl, xr, xlT);
    else         gat_linear_body<false>(x, Wl, bl, Wr, br, xl, xr, xlT);
}

__global__ void gat_mask(const int* __restrict__ adj,
                         unsigned long long* __restrict__ maskT) {
    const int b = blockIdx.y;
    const int i = blockIdx.x * 4 + (threadIdx.x >> 6);
    const int lane = threadIdx.x & 63;
    unsigned long long* mrow = maskT + (size_t)(b * N + i) * NT;
    for (int t = 0; t < NT; ++t) {
        const int j = t * 64 + lane;
        const bool conn = (adj[((size_t)b * N + j) * N + i] != 0) || (j == i);
        const unsigned long long bal = __ballot(conn);
        if (lane == 0) mrow[t] = bal;
    }
}

template <bool F32>
__device__ __forceinline__ void gat_attn_body(
    const float* __restrict__ xl, const float* __restrict__ xr,
    const float* __restrict__ xlT,
    const unsigned long long* __restrict__ maskT,
    const void* __restrict__ att, const void* __restrict__ bias,
    void* __restrict__ out) {
    const int lane = threadIdx.x;         // 0..63 (one wave)
    const int h    = blockIdx.y;          // head
    const int i0   = blockIdx.x * IT;
    const int b    = blockIdx.z;

    __shared__ float a_s[IT][N];          // 4 KB, single-wave private

    float attv[PER_HEAD];
#pragma unroll
    for (int c = 0; c < PER_HEAD; ++c) attv[c] = ldv<F32>(att, h * PER_HEAD + c);
    float xrv[IT][PER_HEAD];
#pragma unroll
    for (int ii = 0; ii < IT; ++ii)
#pragma unroll
        for (int c = 0; c < PER_HEAD; ++c)
            xrv[ii][c] = xr[(b * N + i0 + ii) * OUT_DIM + h * PER_HEAD + c];

    // ---- Phase 1: scores; xlT read as 8 float4 rows per tile ----
    float e[IT][NT];
    const float4* xlT4 = (const float4*)xlT + (size_t)(b * 32 + h * 8) * N;
#pragma unroll
    for (int jt = 0; jt < NT; ++jt) {
        const int j = jt * 64 + lane;
        float xlv[PER_HEAD];
#pragma unroll
        for (int q = 0; q < 8; ++q) {
            const float4 v = xlT4[q * N + j];
            xlv[q * 4 + 0] = v.x;
            xlv[q * 4 + 1] = v.y;
            xlv[q * 4 + 2] = v.z;
            xlv[q * 4 + 3] = v.w;
        }
#pragma unroll
        for (int ii = 0; ii < IT; ++ii) {
            float acc = 0.f;
#pragma unroll
            for (int c = 0; c < PER_HEAD; ++c) {
                const float s = xrv[ii][c] + xlv[c];
                const float lr = fmaxf(s, 0.2f * s);
                acc = fmaf(attv[c], lr, acc);
            }
            const unsigned long long m = maskT[(size_t)(b * N + i0 + ii) * NT + jt];
            e[ii][jt] = ((m >> lane) & 1ull) ? acc : -1e30f;
        }
    }

    // ---- Phase 2: softmax (register), unnormalized alpha -> LDS ----
    float inv[IT];
#pragma unroll
    for (int ii = 0; ii < IT; ++ii) {
        float m = e[ii][0];
#pragma unroll
        for (int t = 1; t < NT; ++t) m = fmaxf(m, e[ii][t]);
#pragma unroll
        for (int d = 1; d < 64; d <<= 1) m = fmaxf(m, __shfl_xor(m, d));
        float ssum = 0.f;
#pragma unroll
        for (int t = 0; t < NT; ++t) {
            const float a = __expf(e[ii][t] - m);
            a_s[ii][t * 64 + lane] = a;
            ssum += a;
        }
#pragma unroll
        for (int d = 1; d < 64; d <<= 1) ssum += __shfl_xor(ssum, d);
        inv[ii] = 1.f / ssum;
    }
    // same wave wrote a_s -> no barrier needed

    // ---- Phase 3: aggregation, unrolled x8 for load ILP ----
    const int c4 = (lane & 7) * 4;
    const int jg = lane >> 3;
    float bv[4];
#pragma unroll
    for (int k = 0; k < 4; ++k) bv[k] = ldv<F32>(bias, h * PER_HEAD + c4 + k);

    const float* xlb = xl + (size_t)(b * N) * OUT_DIM + h * PER_HEAD + c4;

#pragma unroll
    for (int ii = 0; ii < IT; ++ii) {
        float ax = 0.f, ay = 0.f, az = 0.f, aw = 0.f;
#pragma unroll 8
        for (int jo = 0; jo < N / 8; ++jo) {
            const int j = jo * 8 + jg;
            const float av = a_s[ii][j];
            const float4 xv = *(const float4*)(xlb + (size_t)j * OUT_DIM);
            ax = fmaf(av, xv.x, ax);
            ay = fmaf(av, xv.y, ay);
            az = fmaf(av, xv.z, az);
            aw = fmaf(av, xv.w, aw);
        }
#pragma unroll
        for (int d = 8; d < 64; d <<= 1) {
            ax += __shfl_xor(ax, d);
            ay += __shfl_xor(ay, d);
            az += __shfl_xor(az, d);
            aw += __shfl_xor(aw, d);
        }
        if (jg == 0) {
            const float s = inv[ii];
            const float r0 = ax * s + bv[0];
            const float r1 = ay * s + bv[1];
            const float r2 = az * s + bv[2];
            const float r3 = aw * s + bv[3];
            const int ob = (b * N + i0 + ii) * OUT_DIM + h * PER_HEAD + c4;
            if constexpr (F32) {
                *(float4*)((float*)out + ob) = make_float4(r0, r1, r2, r3);
            } else {
                union { ushort4 u; __hip_bfloat16 h4[4]; } cv;
                cv.h4[0] = __float2bfloat16(r0);
                cv.h4[1] = __float2bfloat16(r1);
                cv.h4[2] = __float2bfloat16(r2);
                cv.h4[3] = __float2bfloat16(r3);
                *(ushort4*)((__hip_bfloat16*)out + ob) = cv.u;
            }
        }
    }
}

__global__ __launch_bounds__(64) void gat_attn(
    const float* xl, const float* xr, const float* xlT,
    const unsigned long long* maskT, const void* att,
    const void* bias, const int* __restrict__ flag,
    void* out) {
    if (flag[0]) gat_attn_body<true>(xl, xr, xlT, maskT, att, bias, out);
    else         gat_attn_body<false>(xl, xr, xlT, maskT, att, bias, out);
}

extern "C" void kernel_launch(void* const* d_in, const int* in_sizes, int n_in,
                              void* d_out, int out_size, void* d_ws, size_t ws_size,
                              hipStream_t stream) {
    const void* x    = d_in[0];
    const int*  adj  = (const int*)d_in[1];
    const void* Wl   = d_in[2];
    const void* bl   = d_in[3];
    const void* Wr   = d_in[4];
    const void* br   = d_in[5];
    const void* att  = d_in[6];
    const void* bias = d_in[7];

    char* ws = (char*)d_ws;
    float* xl   = (float*)(ws);                         // 1 MB
    float* xr   = (float*)(ws + (1u << 20));            // 1 MB
    float* xlT  = (float*)(ws + (2u << 20));            // 1 MB
    unsigned long long* maskT =
        (unsigned long long*)(ws + (3u << 20));         // 128 KB
    int* flag = (int*)(ws + (3u << 20) + (1u << 17));

    detect_dtype<<<dim3(1), dim3(256), 0, stream>>>((const unsigned short*)x, flag);
    gat_linear<<<dim3(B * N), dim3(128), 0, stream>>>(x, Wl, bl, Wr, br, flag,
                                                      xl, xr, xlT);
    gat_mask<<<dim3(N / 4, B), dim3(256), 0, stream>>>(adj, maskT);
    gat_attn<<<dim3(N / IT, HEADS, B), dim3(64), 0, stream>>>(xl, xr, xlT, maskT,
                                                              att, bias, flag,
                                                              (void*)d_out);
}

// Round 9
// 111.017 us; speedup vs baseline: 2.5143x; 1.1574x over previous
//
#include <hip/hip_runtime.h>
#include <hip/hip_bf16.h>
#include <math.h>

#define B 4
#define N 512
#define IN_DIM 128
#define OUT_DIM 128
#define HEADS 4
#define PER_HEAD 32
#define NT (N / 64)   // 8 j-tiles of 64
#define IT 2          // target nodes per block (attn)
#define LROWS 4       // rows per block (linear)

// R9. Dtype FULLY resolved: R1/R4/R5 NaNs were all hard-coded-bf16 reads of
// fp32 buffers; detector rounds (R2,R3,R6-R8) all took the F32 branch and
// passed with fp32 float4 output stores. Inputs AND output are fp32.
// -> detector dropped, fp32 hardcoded, R4's verified linear/mask reinstated.
// Attn: leaky(s)=0.6s+0.4|s| => e_ij = 0.6(axr_i+axl_j) + sum_c 0.4att_c|s|
// (axr/axl precomputed in linear); abs() is a free VOP3 modifier => inner
// loop 2 VALU/(i,j,c). Phase-3 jo-outer shares each float4 across IT.

// ---------------------------------------------------------------------------
// Kernel 1: xl = x@Wl+bl ; xr = x@Wr+br (fp32 ws), xlT in channel-group-of-4
// layout, plus axl[b,h,n] = sum_c att_hc*xl, axr likewise (half-wave reduce).
// LROWS rows/block amortize weight loads. 128 thr = one output column each.
// ---------------------------------------------------------------------------
__global__ __launch_bounds__(128) void gat_linear(
    const float* __restrict__ x, const float* __restrict__ Wl,
    const float* __restrict__ bl, const float* __restrict__ Wr,
    const float* __restrict__ br, const float* __restrict__ att,
    float* __restrict__ xl, float* __restrict__ xr, float* __restrict__ xlT,
    float* __restrict__ axl, float* __restrict__ axr) {
    const int r0  = blockIdx.x * LROWS;
    const int col = threadIdx.x;          // col = h*32 + c
    __shared__ float xs[LROWS][IN_DIM];
#pragma unroll
    for (int r = 0; r < LROWS; ++r)
        xs[r][col] = x[(r0 + r) * IN_DIM + col];
    __syncthreads();

    float accl[LROWS], accr[LROWS];
    {
        const float blv = bl[col];
        const float brv = br[col];
#pragma unroll
        for (int r = 0; r < LROWS; ++r) { accl[r] = blv; accr[r] = brv; }
    }
#pragma unroll 8
    for (int k = 0; k < IN_DIM; ++k) {
        const float wl = Wl[k * OUT_DIM + col];
        const float wr = Wr[k * OUT_DIM + col];
#pragma unroll
        for (int r = 0; r < LROWS; ++r) {
            accl[r] = fmaf(xs[r][k], wl, accl[r]);
            accr[r] = fmaf(xs[r][k], wr, accr[r]);
        }
    }
    const float attc = att[col];          // att[h*PER_HEAD + c] == att[col]
    const int h = col >> 5;
#pragma unroll
    for (int r = 0; r < LROWS; ++r) {
        const int row = r0 + r;
        const int b = row >> 9, n = row & (N - 1);
        xl[row * OUT_DIM + col] = accl[r];
        xr[row * OUT_DIM + col] = accr[r];
        xlT[((b * 32 + (col >> 2)) * N + n) * 4 + (col & 3)] = accl[r];
        // att-dot over the 32-lane channel group (lanes [0,31]/[32,63] of wave)
        float pl = attc * accl[r];
        float pr = attc * accr[r];
#pragma unroll
        for (int d = 1; d < 32; d <<= 1) {
            pl += __shfl_xor(pl, d);
            pr += __shfl_xor(pr, d);
        }
        if ((col & 31) == 0) {
            axl[(b * HEADS + h) * N + n] = pl;
            axr[(b * HEADS + h) * N + n] = pr;
        }
    }
}

// ---------------------------------------------------------------------------
// Kernel 2: adjacency bitmask, transposed, diagonal forced. lane <-> i
// (coalesced adj rows); each lane assembles its own u64 over j. (R4 version,
// re-verified; its NaN-era failure was the bf16 read in OTHER kernels.)
// ---------------------------------------------------------------------------
__global__ __launch_bounds__(256) void gat_mask(
    const int* __restrict__ adj, unsigned long long* __restrict__ maskT) {
    const int b    = blockIdx.y;
    const int i    = blockIdx.x * 64 + (threadIdx.x & 63);
    const int wave = threadIdx.x >> 6;
    for (int t = wave; t < NT; t += 4) {
        unsigned long long m = 0ull;
#pragma unroll 8
        for (int jj = 0; jj < 64; ++jj) {
            const int j = t * 64 + jj;
            const int v = adj[((size_t)b * N + j) * N + i];
            m |= (unsigned long long)(v != 0) << jj;
        }
        if ((i >> 6) == t) m |= 1ull << (i & 63);   // self-loop
        maskT[(size_t)(b * N + i) * NT + t] = m;
    }
}

// ---------------------------------------------------------------------------
// Kernel 3: fused scores + segment-softmax + aggregation. 1 wave per block.
// ---------------------------------------------------------------------------
__global__ __launch_bounds__(64) void gat_attn(
    const float* __restrict__ xl, const float* __restrict__ xr,
    const float* __restrict__ xlT, const float* __restrict__ axl,
    const float* __restrict__ axr,
    const unsigned long long* __restrict__ maskT,
    const float* __restrict__ att, const float* __restrict__ bias,
    float* __restrict__ out) {
    const int lane = threadIdx.x;         // 0..63 (one wave)
    const int h    = blockIdx.y;          // head
    const int i0   = blockIdx.x * IT;
    const int b    = blockIdx.z;

    __shared__ float a_s[IT][N];          // 4 KB

    float att04[PER_HEAD];                // 0.4 * att
#pragma unroll
    for (int c = 0; c < PER_HEAD; ++c) att04[c] = 0.4f * att[h * PER_HEAD + c];
    float xrv[IT][PER_HEAD];
#pragma unroll
    for (int ii = 0; ii < IT; ++ii)
#pragma unroll
        for (int c = 0; c < PER_HEAD; ++c)
            xrv[ii][c] = xr[(b * N + i0 + ii) * OUT_DIM + h * PER_HEAD + c];
    float axr_i[IT];
#pragma unroll
    for (int ii = 0; ii < IT; ++ii)
        axr_i[ii] = axr[(b * HEADS + h) * N + i0 + ii];

    // ---- Phase 1: scores; 2 VALU per (i,j,c) via abs-modifier ----
    float e[IT][NT];
    const float4* xlT4 = (const float4*)xlT + (size_t)(b * 32 + h * 8) * N;
    const float*  axlh = axl + (size_t)(b * HEADS + h) * N;
#pragma unroll
    for (int jt = 0; jt < NT; ++jt) {
        const int j = jt * 64 + lane;
        const float alj = axlh[j];
        float xlv[PER_HEAD];
#pragma unroll
        for (int q = 0; q < 8; ++q) {
            const float4 v = xlT4[q * N + j];
            xlv[q * 4 + 0] = v.x;
            xlv[q * 4 + 1] = v.y;
            xlv[q * 4 + 2] = v.z;
            xlv[q * 4 + 3] = v.w;
        }
#pragma unroll
        for (int ii = 0; ii < IT; ++ii) {
            float acc = 0.f;
#pragma unroll
            for (int c = 0; c < PER_HEAD; ++c) {
                const float s = xrv[ii][c] + xlv[c];
                acc = fmaf(att04[c], fabsf(s), acc);   // free VOP3 abs()
            }
            const float ev = fmaf(0.6f, axr_i[ii] + alj, acc);
            const unsigned long long m = maskT[(size_t)(b * N + i0 + ii) * NT + jt];
            e[ii][jt] = ((m >> lane) & 1ull) ? ev : -1e30f;
        }
    }

    // ---- Phase 2: softmax (register), unnormalized alpha -> LDS ----
    float inv[IT];
#pragma unroll
    for (int ii = 0; ii < IT; ++ii) {
        float m = e[ii][0];
#pragma unroll
        for (int t = 1; t < NT; ++t) m = fmaxf(m, e[ii][t]);
#pragma unroll
        for (int d = 1; d < 64; d <<= 1) m = fmaxf(m, __shfl_xor(m, d));
        float ssum = 0.f;
#pragma unroll
        for (int t = 0; t < NT; ++t) {
            const float a = __expf(e[ii][t] - m);
            a_s[ii][t * 64 + lane] = a;
            ssum += a;
        }
#pragma unroll
        for (int d = 1; d < 64; d <<= 1) ssum += __shfl_xor(ssum, d);
        inv[ii] = 1.f / ssum;
    }
    // same wave wrote a_s -> no barrier needed

    // ---- Phase 3: aggregation; jo-outer shares each float4 across IT ----
    const int c4 = (lane & 7) * 4;
    const int jg = lane >> 3;
    const float* xlb = xl + (size_t)(b * N) * OUT_DIM + h * PER_HEAD + c4;

    float ax[IT], ay[IT], az[IT], aw[IT];
#pragma unroll
    for (int ii = 0; ii < IT; ++ii) { ax[ii] = ay[ii] = az[ii] = aw[ii] = 0.f; }

#pragma unroll 8
    for (int jo = 0; jo < N / 8; ++jo) {
        const int j = jo * 8 + jg;
        const float4 xv = *(const float4*)(xlb + (size_t)j * OUT_DIM);
#pragma unroll
        for (int ii = 0; ii < IT; ++ii) {
            const float av = a_s[ii][j];
            ax[ii] = fmaf(av, xv.x, ax[ii]);
            ay[ii] = fmaf(av, xv.y, ay[ii]);
            az[ii] = fmaf(av, xv.z, az[ii]);
            aw[ii] = fmaf(av, xv.w, aw[ii]);
        }
    }

#pragma unroll
    for (int ii = 0; ii < IT; ++ii) {
        float rx = ax[ii], ry = ay[ii], rz = az[ii], rw = aw[ii];
#pragma unroll
        for (int d = 8; d < 64; d <<= 1) {
            rx += __shfl_xor(rx, d);
            ry += __shfl_xor(ry, d);
            rz += __shfl_xor(rz, d);
            rw += __shfl_xor(rw, d);
        }
        if (jg == 0) {
            const float s = inv[ii];
            const int ob = (b * N + i0 + ii) * OUT_DIM + h * PER_HEAD + c4;
            const float4 r = make_float4(rx * s + bias[h * PER_HEAD + c4 + 0],
                                         ry * s + bias[h * PER_HEAD + c4 + 1],
                                         rz * s + bias[h * PER_HEAD + c4 + 2],
                                         rw * s + bias[h * PER_HEAD + c4 + 3]);
            *(float4*)(out + ob) = r;
        }
    }
}

extern "C" void kernel_launch(void* const* d_in, const int* in_sizes, int n_in,
                              void* d_out, int out_size, void* d_ws, size_t ws_size,
                              hipStream_t stream) {
    const float* x    = (const float*)d_in[0];
    const int*   adj  = (const int*)d_in[1];
    const float* Wl   = (const float*)d_in[2];
    const float* bl   = (const float*)d_in[3];
    const float* Wr   = (const float*)d_in[4];
    const float* br   = (const float*)d_in[5];
    const float* att  = (const float*)d_in[6];
    const float* bias = (const float*)d_in[7];
    float* out = (float*)d_out;

    char* ws = (char*)d_ws;
    float* xl   = (float*)(ws);                         // 1 MB
    float* xr   = (float*)(ws + (1u << 20));            // 1 MB
    float* xlT  = (float*)(ws + (2u << 20));            // 1 MB
    unsigned long long* maskT =
        (unsigned long long*)(ws + (3u << 20));         // 128 KB
    float* axl  = (float*)(ws + (3u << 20) + (1u << 17));            // 32 KB
    float* axr  = (float*)(ws + (3u << 20) + (1u << 17) + (1u << 15)); // 32 KB

    gat_linear<<<dim3(B * N / LROWS), dim3(128), 0, stream>>>(
        x, Wl, bl, Wr, br, att, xl, xr, xlT, axl, axr);
    gat_mask<<<dim3(N / 64, B), dim3(256), 0, stream>>>(adj, maskT);
    gat_attn<<<dim3(N / IT, HEADS, B), dim3(64), 0, stream>>>(
        xl, xr, xlT, axl, axr, maskT, att, bias, out);
}